// Round 1
// baseline (224.976 us; speedup 1.0000x reference)
//
#include <hip/hip_runtime.h>

// ---------------------------------------------------------------------------
// TripletLossWithHardMining  (B=4096, D=1024, fp32 in, fp32 scalar out)
//
// Plan:
//  K1 row_stats : per-row sum/sqnorm of a,p,n; d_ap, d_an_row; bf16 copies of
//                 a,p,n into ws; init hard_n=0 / hard_p=+inf bit slots.
//  K2 gemm_mask : tiled bf16 MFMA GEMM (A·N^T and A·P^T via grid.z), distance
//                 from the expansion formula, masked row max/min reduced
//                 in-register, combined with atomicMax/atomicMin on uint bits
//                 (positive floats order as uints).
//  K3 finalize  : d_an = mean(hard_n), d_pp = mean(hard_p, inf->0),
//                 loss = mean(relu(d_ap - 0.5*d_pp - 0.5*d_an + 1)).
// ---------------------------------------------------------------------------

#define NB 4096
#define DIM 1024
#define EPSF 1e-6f
#define D_EPS2 (1024.0f * 1e-6f * 1e-6f)

#define BM 128           // tile (rows and cols)
#define BK 32            // k-tile
#define LDK 40           // padded LDS k-stride (bf16 elems), 80B rows, 16B aligned

typedef __bf16  bf16x8 __attribute__((ext_vector_type(8)));
typedef float   f32x4  __attribute__((ext_vector_type(4)));

__device__ __forceinline__ unsigned short f2bf(float x) {
    unsigned u = __float_as_uint(x);
    u += 0x7FFFu + ((u >> 16) & 1u);   // round-to-nearest-even
    return (unsigned short)(u >> 16);
}

// stats layout (float slots of NB each):
// 0:sum_a 1:nrm_a 2:sum_p 3:nrm_p 4:sum_n 5:nrm_n 6:d_ap 7:d_an_row
// 8:hard_n(uint bits) 9:hard_p(uint bits)

__global__ __launch_bounds__(256) void row_stats_kernel(
    const float* __restrict__ a, const float* __restrict__ p,
    const float* __restrict__ n,
    unsigned short* __restrict__ abf, unsigned short* __restrict__ pbf,
    unsigned short* __restrict__ nbf, float* __restrict__ stats)
{
    const int row = blockIdx.x;
    const int t   = threadIdx.x;
    const size_t base = (size_t)row * DIM;

    // one float4 per thread: 256 threads * 4 = 1024 elements
    float4 va = ((const float4*)(a + base))[t];
    float4 vp = ((const float4*)(p + base))[t];
    float4 vn = ((const float4*)(n + base))[t];

    float v[8] = {0,0,0,0,0,0,0,0};   // sa qa sp qp sn qn dap2 dan2
    const float fa[4] = {va.x, va.y, va.z, va.w};
    const float fp[4] = {vp.x, vp.y, vp.z, vp.w};
    const float fn[4] = {vn.x, vn.y, vn.z, vn.w};
#pragma unroll
    for (int e = 0; e < 4; e++) {
        v[0] += fa[e];           v[1] += fa[e] * fa[e];
        v[2] += fp[e];           v[3] += fp[e] * fp[e];
        v[4] += fn[e];           v[5] += fn[e] * fn[e];
        float dp = fa[e] - fp[e] + EPSF;  v[6] += dp * dp;
        float dn = fa[e] - fn[e] + EPSF;  v[7] += dn * dn;
    }

    // write bf16 copies (8 bytes per thread per matrix)
    ushort4 ba, bp, bn;
    ba.x = f2bf(fa[0]); ba.y = f2bf(fa[1]); ba.z = f2bf(fa[2]); ba.w = f2bf(fa[3]);
    bp.x = f2bf(fp[0]); bp.y = f2bf(fp[1]); bp.z = f2bf(fp[2]); bp.w = f2bf(fp[3]);
    bn.x = f2bf(fn[0]); bn.y = f2bf(fn[1]); bn.z = f2bf(fn[2]); bn.w = f2bf(fn[3]);
    ((ushort4*)(abf + base))[t] = ba;
    ((ushort4*)(pbf + base))[t] = bp;
    ((ushort4*)(nbf + base))[t] = bn;

    // block reduce 8 quantities
#pragma unroll
    for (int m = 32; m >= 1; m >>= 1)
#pragma unroll
        for (int q = 0; q < 8; q++) v[q] += __shfl_xor(v[q], m);

    __shared__ float part[4][8];
    const int wave = t >> 6, lane = t & 63;
    if (lane == 0)
#pragma unroll
        for (int q = 0; q < 8; q++) part[wave][q] = v[q];
    __syncthreads();
    if (t == 0) {
        float r[8];
#pragma unroll
        for (int q = 0; q < 8; q++)
            r[q] = part[0][q] + part[1][q] + part[2][q] + part[3][q];
        stats[0 * NB + row] = r[0];
        stats[1 * NB + row] = r[1];
        stats[2 * NB + row] = r[2];
        stats[3 * NB + row] = r[3];
        stats[4 * NB + row] = r[4];
        stats[5 * NB + row] = r[5];
        stats[6 * NB + row] = sqrtf(r[6]);
        stats[7 * NB + row] = sqrtf(r[7]);
        ((unsigned*)stats)[8 * NB + row] = 0u;            // hard_n: max identity
        ((unsigned*)stats)[9 * NB + row] = 0x7f800000u;   // hard_p: +inf
    }
}

// grid (32, 32, 2): z=0 -> negatives (masked max, cutoff d_ap)
//                   z=1 -> positives (masked min, cutoff d_an_row)
__global__ __launch_bounds__(256, 2) void gemm_mask_kernel(
    const unsigned short* __restrict__ Abf,
    const unsigned short* __restrict__ Nbf,
    const unsigned short* __restrict__ Pbf,
    float* __restrict__ stats)
{
    const int i0 = blockIdx.x * BM;
    const int j0 = blockIdx.y * BM;
    const bool isP = (blockIdx.z != 0);
    const unsigned short* __restrict__ Bmat = isP ? Pbf : Nbf;

    __shared__ unsigned short sA[BM * LDK];
    __shared__ unsigned short sB[BM * LDK];

    const int t    = threadIdx.x;
    const int wave = t >> 6, lane = t & 63;
    const int wm   = wave >> 1, wn = wave & 1;
    const int quad = lane >> 4, lrow = lane & 15;

    f32x4 acc[4][4];
#pragma unroll
    for (int im = 0; im < 4; im++)
#pragma unroll
        for (int jn = 0; jn < 4; jn++) acc[im][jn] = (f32x4)(0.0f);

    for (int kt = 0; kt < DIM; kt += BK) {
        __syncthreads();   // protect LDS from previous iteration's readers
        // stage A and B tiles: 512 16B-chunks each of 8 bf16; 2 chunks/thread/tile
#pragma unroll
        for (int c = t; c < 512; c += 256) {
            const int row = c >> 2;
            const int ko  = (c & 3) * 8;
            *(uint4*)(sA + row * LDK + ko) =
                *(const uint4*)(Abf + (size_t)(i0 + row) * DIM + kt + ko);
            *(uint4*)(sB + row * LDK + ko) =
                *(const uint4*)(Bmat + (size_t)(j0 + row) * DIM + kt + ko);
        }
        __syncthreads();

        bf16x8 afr[4], bfr[4];
#pragma unroll
        for (int im = 0; im < 4; im++)
            afr[im] = *(const bf16x8*)(sA + (wm * 64 + im * 16 + lrow) * LDK + quad * 8);
#pragma unroll
        for (int jn = 0; jn < 4; jn++)
            bfr[jn] = *(const bf16x8*)(sB + (wn * 64 + jn * 16 + lrow) * LDK + quad * 8);
#pragma unroll
        for (int im = 0; im < 4; im++)
#pragma unroll
            for (int jn = 0; jn < 4; jn++)
                acc[im][jn] = __builtin_amdgcn_mfma_f32_16x16x32_bf16(
                    afr[im], bfr[jn], acc[im][jn], 0, 0, 0);
    }

    // epilogue: distance + mask + row reduce + atomic
    const float* __restrict__ sum_a = stats + 0 * NB;
    const float* __restrict__ nrm_a = stats + 1 * NB;
    const float* __restrict__ sum_b = isP ? (stats + 2 * NB) : (stats + 4 * NB);
    const float* __restrict__ nrm_b = isP ? (stats + 3 * NB) : (stats + 5 * NB);
    const float* __restrict__ cut_v = isP ? (stats + 7 * NB) : (stats + 6 * NB);
    unsigned* __restrict__ hard = ((unsigned*)stats) + (isP ? 9 : 8) * NB;

#pragma unroll
    for (int im = 0; im < 4; im++) {
#pragma unroll
        for (int r = 0; r < 4; r++) {
            const int gi = i0 + wm * 64 + im * 16 + quad * 4 + r;
            const float cut    = cut_v[gi];
            const float base_i = nrm_a[gi] + 2.0f * EPSF * sum_a[gi] + D_EPS2;
            float best = isP ? __uint_as_float(0x7f800000u) : 0.0f;
#pragma unroll
            for (int jn = 0; jn < 4; jn++) {
                const int gj = j0 + wn * 64 + jn * 16 + lrow;
                const float c  = acc[im][jn][r];
                const float sq = base_i + nrm_b[gj] - 2.0f * c - 2.0f * EPSF * sum_b[gj];
                const float dist = sqrtf(fmaxf(sq, 0.0f));
                if (isP) { if (dist > cut && dist < best) best = dist; }
                else     { if (dist < cut && dist > best) best = dist; }
            }
            // reduce across the 16 lanes of this quad (cols)
#pragma unroll
            for (int m = 1; m < 16; m <<= 1) {
                float o = __shfl_xor(best, m);
                best = isP ? fminf(best, o) : fmaxf(best, o);
            }
            if (lrow == 0) {
                const unsigned bits = __float_as_uint(best);
                if (isP) { if (bits != 0x7f800000u) atomicMin(hard + gi, bits); }
                else     { if (bits != 0u)          atomicMax(hard + gi, bits); }
            }
        }
    }
}

__global__ __launch_bounds__(256) void finalize_kernel(
    const float* __restrict__ stats, float* __restrict__ out)
{
    const unsigned* hard_n = ((const unsigned*)stats) + 8 * NB;
    const unsigned* hard_p = ((const unsigned*)stats) + 9 * NB;
    const float*    d_ap   = stats + 6 * NB;
    const int t = threadIdx.x;
    const int wave = t >> 6, lane = t & 63;
    __shared__ float pn[4], pp[4];
    __shared__ float s_dan, s_dpp;

    float sn = 0.0f, sp = 0.0f;
    for (int i = t; i < NB; i += 256) {
        sn += __uint_as_float(hard_n[i]);
        const unsigned hp = hard_p[i];
        if (hp != 0x7f800000u) sp += __uint_as_float(hp);
    }
#pragma unroll
    for (int m = 32; m >= 1; m >>= 1) {
        sn += __shfl_xor(sn, m);
        sp += __shfl_xor(sp, m);
    }
    if (lane == 0) { pn[wave] = sn; pp[wave] = sp; }
    __syncthreads();
    if (t == 0) {
        s_dan = (pn[0] + pn[1] + pn[2] + pn[3]) / (float)NB;
        s_dpp = (pp[0] + pp[1] + pp[2] + pp[3]) / (float)NB;
    }
    __syncthreads();
    const float dan = s_dan, dpp = s_dpp;

    float accv = 0.0f;
    for (int i = t; i < NB; i += 256)
        accv += fmaxf(d_ap[i] - 0.5f * dpp - 0.5f * dan + 1.0f, 0.0f);
#pragma unroll
    for (int m = 32; m >= 1; m >>= 1) accv += __shfl_xor(accv, m);
    if (lane == 0) pn[wave] = accv;
    __syncthreads();
    if (t == 0) out[0] = (pn[0] + pn[1] + pn[2] + pn[3]) / (float)NB;
}

extern "C" void kernel_launch(void* const* d_in, const int* in_sizes, int n_in,
                              void* d_out, int out_size, void* d_ws, size_t ws_size,
                              hipStream_t stream) {
    const float* a = (const float*)d_in[0];
    const float* p = (const float*)d_in[1];
    const float* n = (const float*)d_in[2];
    float* out = (float*)d_out;

    // ws layout: abf | pbf | nbf | stats(10*NB floats)  => ~25.3 MB
    unsigned short* abf = (unsigned short*)d_ws;
    unsigned short* pbf = abf + (size_t)NB * DIM;
    unsigned short* nbf = pbf + (size_t)NB * DIM;
    float* stats = (float*)(nbf + (size_t)NB * DIM);

    row_stats_kernel<<<NB, 256, 0, stream>>>(a, p, n, abf, pbf, nbf, stats);

    dim3 grid(NB / BM, NB / BM, 2);
    gemm_mask_kernel<<<grid, 256, 0, stream>>>(abf, nbf, pbf, stats);

    finalize_kernel<<<1, 256, 0, stream>>>(stats, out);
}

// Round 2
// 217.487 us; speedup vs baseline: 1.0344x; 1.0344x over previous
//
#include <hip/hip_runtime.h>

// ---------------------------------------------------------------------------
// TripletLossWithHardMining  (B=4096, D=1024, fp32 in, fp32 scalar out)
//
//  K1 row_stats : per-row sum/sqnorm of a,p,n; d_ap, d_an_row; bf16 copies of
//                 a,p,n into ws; init hard_n=0 / hard_p=+inf bit slots.
//  K2 gemm_mask : tiled bf16 MFMA GEMM (A·N^T and A·P^T via grid.z) with
//                 global_load_lds(16B) staging + XOR bank swizzle; distance
//                 via expansion, masked row max/min reduced in-register,
//                 combined with atomicMax/atomicMin on uint bits.
//  K3 finalize  : d_an = mean(hard_n), d_pp = mean(hard_p, inf->0),
//                 loss = mean(relu(d_ap - 0.5*d_pp - 0.5*d_an + 1)).
// ---------------------------------------------------------------------------

#define NB 4096
#define DIM 1024
#define EPSF 1e-6f
#define D_EPS2 (1024.0f * 1e-6f * 1e-6f)

#define BM 128           // tile (rows and cols)
#define BK 32            // k-tile (bf16 elems) -> 64 B rows, unpadded

typedef __bf16  bf16x8 __attribute__((ext_vector_type(8)));
typedef float   f32x4  __attribute__((ext_vector_type(4)));

__device__ __forceinline__ unsigned short f2bf(float x) {
    unsigned u = __float_as_uint(x);
    u += 0x7FFFu + ((u >> 16) & 1u);   // round-to-nearest-even
    return (unsigned short)(u >> 16);
}

// async 16B/lane global->LDS; lds base must be wave-uniform, data lands at
// ldsbase + lane*16.
__device__ __forceinline__ void g2l16(const unsigned short* g, unsigned short* l) {
    __builtin_amdgcn_global_load_lds(
        (const __attribute__((address_space(1))) unsigned int*)g,
        (__attribute__((address_space(3))) unsigned int*)l, 16, 0, 0);
}

// stats layout (float slots of NB each):
// 0:sum_a 1:nrm_a 2:sum_p 3:nrm_p 4:sum_n 5:nrm_n 6:d_ap 7:d_an_row
// 8:hard_n(uint bits) 9:hard_p(uint bits)

__global__ __launch_bounds__(256) void row_stats_kernel(
    const float* __restrict__ a, const float* __restrict__ p,
    const float* __restrict__ n,
    unsigned short* __restrict__ abf, unsigned short* __restrict__ pbf,
    unsigned short* __restrict__ nbf, float* __restrict__ stats)
{
    const int row = blockIdx.x;
    const int t   = threadIdx.x;
    const size_t base = (size_t)row * DIM;

    float4 va = ((const float4*)(a + base))[t];
    float4 vp = ((const float4*)(p + base))[t];
    float4 vn = ((const float4*)(n + base))[t];

    float v[8] = {0,0,0,0,0,0,0,0};   // sa qa sp qp sn qn dap2 dan2
    const float fa[4] = {va.x, va.y, va.z, va.w};
    const float fp[4] = {vp.x, vp.y, vp.z, vp.w};
    const float fn[4] = {vn.x, vn.y, vn.z, vn.w};
#pragma unroll
    for (int e = 0; e < 4; e++) {
        v[0] += fa[e];           v[1] += fa[e] * fa[e];
        v[2] += fp[e];           v[3] += fp[e] * fp[e];
        v[4] += fn[e];           v[5] += fn[e] * fn[e];
        float dp = fa[e] - fp[e] + EPSF;  v[6] += dp * dp;
        float dn = fa[e] - fn[e] + EPSF;  v[7] += dn * dn;
    }

    ushort4 ba, bp, bn;
    ba.x = f2bf(fa[0]); ba.y = f2bf(fa[1]); ba.z = f2bf(fa[2]); ba.w = f2bf(fa[3]);
    bp.x = f2bf(fp[0]); bp.y = f2bf(fp[1]); bp.z = f2bf(fp[2]); bp.w = f2bf(fp[3]);
    bn.x = f2bf(fn[0]); bn.y = f2bf(fn[1]); bn.z = f2bf(fn[2]); bn.w = f2bf(fn[3]);
    ((ushort4*)(abf + base))[t] = ba;
    ((ushort4*)(pbf + base))[t] = bp;
    ((ushort4*)(nbf + base))[t] = bn;

#pragma unroll
    for (int m = 32; m >= 1; m >>= 1)
#pragma unroll
        for (int q = 0; q < 8; q++) v[q] += __shfl_xor(v[q], m);

    __shared__ float part[4][8];
    const int wave = t >> 6, lane = t & 63;
    if (lane == 0)
#pragma unroll
        for (int q = 0; q < 8; q++) part[wave][q] = v[q];
    __syncthreads();
    if (t == 0) {
        float r[8];
#pragma unroll
        for (int q = 0; q < 8; q++)
            r[q] = part[0][q] + part[1][q] + part[2][q] + part[3][q];
        stats[0 * NB + row] = r[0];
        stats[1 * NB + row] = r[1];
        stats[2 * NB + row] = r[2];
        stats[3 * NB + row] = r[3];
        stats[4 * NB + row] = r[4];
        stats[5 * NB + row] = r[5];
        stats[6 * NB + row] = sqrtf(r[6]);
        stats[7 * NB + row] = sqrtf(r[7]);
        ((unsigned*)stats)[8 * NB + row] = 0u;            // hard_n: max identity
        ((unsigned*)stats)[9 * NB + row] = 0x7f800000u;   // hard_p: +inf
    }
}

// grid (32, 32, 2): z=0 -> negatives (masked max, cutoff d_ap)
//                   z=1 -> positives (masked min, cutoff d_an_row)
__global__ __launch_bounds__(256, 2) void gemm_mask_kernel(
    const unsigned short* __restrict__ Abf,
    const unsigned short* __restrict__ Nbf,
    const unsigned short* __restrict__ Pbf,
    float* __restrict__ stats)
{
    const int i0 = blockIdx.x * BM;
    const int j0 = blockIdx.y * BM;
    const bool isP = (blockIdx.z != 0);
    const unsigned short* __restrict__ Bmat = isP ? Pbf : Nbf;

    __shared__ unsigned short sA[BM * BK];   // 8 KB, unpadded (global_load_lds)
    __shared__ unsigned short sB[BM * BK];

    const int t    = threadIdx.x;
    const int wave = t >> 6, lane = t & 63;
    const int wm   = wave >> 1, wn = wave & 1;
    const int quad = lane >> 4, lrow = lane & 15;

    // ---- staging pointers (hoisted; only incremented in the K-loop) ----
    // Each wave stages 32 rows of A and 32 rows of B per k-tile via 2+2
    // global_load_lds(16B) instrs. LDS slot of lane = base + lane*16B, i.e.
    // (row_local = lane>>2, slot = lane&3). XOR swizzle: logical chunk
    // j_log = slot ^ ((row>>1)&3) is what must be loaded into this slot.
    const int lrow4 = lane >> 2;                                  // 0..15
    const int kch   = ((lane & 3) ^ ((lane >> 3) & 3)) * 8;       // elem offset
    const unsigned short* ga0 = Abf  + (size_t)(i0 + wave * 32 + lrow4) * DIM + kch;
    const unsigned short* ga1 = ga0 + 16 * DIM;
    const unsigned short* gb0 = Bmat + (size_t)(j0 + wave * 32 + lrow4) * DIM + kch;
    const unsigned short* gb1 = gb0 + 16 * DIM;
    unsigned short* la0 = sA + (wave * 32) * BK;
    unsigned short* la1 = la0 + 16 * BK;
    unsigned short* lb0 = sB + (wave * 32) * BK;
    unsigned short* lb1 = lb0 + 16 * BK;

    // ---- fragment read pointers (swizzled chunk) ----
    const int rsw = (quad ^ ((lrow >> 1) & 3)) * 8;   // swizzled chunk elem off
    const unsigned short* pa = sA + (wm * 64 + lrow) * BK + rsw;
    const unsigned short* pb = sB + (wn * 64 + lrow) * BK + rsw;

    f32x4 acc[4][4];
#pragma unroll
    for (int im = 0; im < 4; im++)
#pragma unroll
        for (int jn = 0; jn < 4; jn++) acc[im][jn] = (f32x4)(0.0f);

    for (int kt = 0; kt < DIM; kt += BK) {
        __syncthreads();   // protect LDS from previous iteration's readers
        g2l16(ga0, la0);
        g2l16(ga1, la1);
        g2l16(gb0, lb0);
        g2l16(gb1, lb1);
        ga0 += BK; ga1 += BK; gb0 += BK; gb1 += BK;
        __syncthreads();   // drains vmcnt (global_load_lds) before reads

        bf16x8 afr[4], bfr[4];
#pragma unroll
        for (int im = 0; im < 4; im++)
            afr[im] = *(const bf16x8*)(pa + im * 16 * BK);
#pragma unroll
        for (int jn = 0; jn < 4; jn++)
            bfr[jn] = *(const bf16x8*)(pb + jn * 16 * BK);
#pragma unroll
        for (int im = 0; im < 4; im++)
#pragma unroll
            for (int jn = 0; jn < 4; jn++)
                acc[im][jn] = __builtin_amdgcn_mfma_f32_16x16x32_bf16(
                    afr[im], bfr[jn], acc[im][jn], 0, 0, 0);
    }

    // epilogue: distance + mask + row reduce + atomic
    const float* __restrict__ sum_a = stats + 0 * NB;
    const float* __restrict__ nrm_a = stats + 1 * NB;
    const float* __restrict__ sum_b = isP ? (stats + 2 * NB) : (stats + 4 * NB);
    const float* __restrict__ nrm_b = isP ? (stats + 3 * NB) : (stats + 5 * NB);
    const float* __restrict__ cut_v = isP ? (stats + 7 * NB) : (stats + 6 * NB);
    unsigned* __restrict__ hard = ((unsigned*)stats) + (isP ? 9 : 8) * NB;

#pragma unroll
    for (int im = 0; im < 4; im++) {
#pragma unroll
        for (int r = 0; r < 4; r++) {
            const int gi = i0 + wm * 64 + im * 16 + quad * 4 + r;
            const float cut    = cut_v[gi];
            const float base_i = nrm_a[gi] + 2.0f * EPSF * sum_a[gi] + D_EPS2;
            float best = isP ? __uint_as_float(0x7f800000u) : 0.0f;
#pragma unroll
            for (int jn = 0; jn < 4; jn++) {
                const int gj = j0 + wn * 64 + jn * 16 + lrow;
                const float c  = acc[im][jn][r];
                const float sq = base_i + nrm_b[gj] - 2.0f * c - 2.0f * EPSF * sum_b[gj];
                const float dist = sqrtf(fmaxf(sq, 0.0f));
                if (isP) { if (dist > cut && dist < best) best = dist; }
                else     { if (dist < cut && dist > best) best = dist; }
            }
#pragma unroll
            for (int m = 1; m < 16; m <<= 1) {
                float o = __shfl_xor(best, m);
                best = isP ? fminf(best, o) : fmaxf(best, o);
            }
            if (lrow == 0) {
                const unsigned bits = __float_as_uint(best);
                if (isP) { if (bits != 0x7f800000u) atomicMin(hard + gi, bits); }
                else     { if (bits != 0u)          atomicMax(hard + gi, bits); }
            }
        }
    }
}

__global__ __launch_bounds__(256) void finalize_kernel(
    const float* __restrict__ stats, float* __restrict__ out)
{
    const unsigned* hard_n = ((const unsigned*)stats) + 8 * NB;
    const unsigned* hard_p = ((const unsigned*)stats) + 9 * NB;
    const float*    d_ap   = stats + 6 * NB;
    const int t = threadIdx.x;
    const int wave = t >> 6, lane = t & 63;
    __shared__ float pn[4], pp[4];
    __shared__ float s_dan, s_dpp;

    float sn = 0.0f, sp = 0.0f;
    for (int i = t; i < NB; i += 256) {
        sn += __uint_as_float(hard_n[i]);
        const unsigned hp = hard_p[i];
        if (hp != 0x7f800000u) sp += __uint_as_float(hp);
    }
#pragma unroll
    for (int m = 32; m >= 1; m >>= 1) {
        sn += __shfl_xor(sn, m);
        sp += __shfl_xor(sp, m);
    }
    if (lane == 0) { pn[wave] = sn; pp[wave] = sp; }
    __syncthreads();
    if (t == 0) {
        s_dan = (pn[0] + pn[1] + pn[2] + pn[3]) / (float)NB;
        s_dpp = (pp[0] + pp[1] + pp[2] + pp[3]) / (float)NB;
    }
    __syncthreads();
    const float dan = s_dan, dpp = s_dpp;

    float accv = 0.0f;
    for (int i = t; i < NB; i += 256)
        accv += fmaxf(d_ap[i] - 0.5f * dpp - 0.5f * dan + 1.0f, 0.0f);
#pragma unroll
    for (int m = 32; m >= 1; m >>= 1) accv += __shfl_xor(accv, m);
    if (lane == 0) pn[wave] = accv;
    __syncthreads();
    if (t == 0) out[0] = (pn[0] + pn[1] + pn[2] + pn[3]) / (float)NB;
}

extern "C" void kernel_launch(void* const* d_in, const int* in_sizes, int n_in,
                              void* d_out, int out_size, void* d_ws, size_t ws_size,
                              hipStream_t stream) {
    const float* a = (const float*)d_in[0];
    const float* p = (const float*)d_in[1];
    const float* n = (const float*)d_in[2];
    float* out = (float*)d_out;

    // ws layout: abf | pbf | nbf | stats(10*NB floats)  => ~25.3 MB
    unsigned short* abf = (unsigned short*)d_ws;
    unsigned short* pbf = abf + (size_t)NB * DIM;
    unsigned short* nbf = pbf + (size_t)NB * DIM;
    float* stats = (float*)(nbf + (size_t)NB * DIM);

    row_stats_kernel<<<NB, 256, 0, stream>>>(a, p, n, abf, pbf, nbf, stats);

    dim3 grid(NB / BM, NB / BM, 2);
    gemm_mask_kernel<<<grid, 256, 0, stream>>>(abf, nbf, pbf, stats);

    finalize_kernel<<<1, 256, 0, stream>>>(stats, out);
}

// Round 3
// 195.185 us; speedup vs baseline: 1.1526x; 1.1143x over previous
//
#include <hip/hip_runtime.h>

// ---------------------------------------------------------------------------
// TripletLossWithHardMining  (B=4096, D=1024, fp32 in, fp32 scalar out)
//
//  K1 row_stats : per-row combined constants; d_ap, d_an_row; bf16 copies of
//                 a,p,n; init hard_n=0 / hard_p=+inf bit slots.
//  K2 gemm_mask : FUSED bf16 MFMA GEMM computing A·N^T and A·P^T in one
//                 block (A tile staged once, 32 MFMA per wave per k-iter),
//                 global_load_lds(16B) staging + XOR bank swizzle; distance
//                 via expansion, masked row max/min reduced in-register,
//                 combined with atomicMax/atomicMin on uint bits.
//  K3 finalize  : d_an = mean(hard_n), d_pp = mean(hard_p, inf->0),
//                 loss = mean(relu(d_ap - 0.5*d_pp - 0.5*d_an + 1)).
// ---------------------------------------------------------------------------

#define NB 4096
#define DIM 1024
#define EPSF 1e-6f
#define D_EPS2 (1024.0f * 1e-6f * 1e-6f)

#define BM 128           // tile (rows and cols)
#define BK 32            // k-tile (bf16 elems) -> 64 B rows, unpadded

typedef __bf16  bf16x8 __attribute__((ext_vector_type(8)));
typedef float   f32x4  __attribute__((ext_vector_type(4)));

__device__ __forceinline__ unsigned short f2bf(float x) {
    unsigned u = __float_as_uint(x);
    u += 0x7FFFu + ((u >> 16) & 1u);   // round-to-nearest-even
    return (unsigned short)(u >> 16);
}

// async 16B/lane global->LDS; lds base wave-uniform, data lands at base+lane*16
__device__ __forceinline__ void g2l16(const unsigned short* g, unsigned short* l) {
    __builtin_amdgcn_global_load_lds(
        (const __attribute__((address_space(1))) unsigned int*)g,
        (__attribute__((address_space(3))) unsigned int*)l, 16, 0, 0);
}

// stats layout (NB-float slots):
// 0: base_a[i] = |a_i|^2 + 2e*sum_a + D*e^2
// 1: cn[j]     = |n_j|^2 - 2e*sum_n
// 2: cp[j]     = |p_j|^2 - 2e*sum_p
// 3: d_ap   4: d_an_row   5: hard_n bits   6: hard_p bits

__global__ __launch_bounds__(256) void row_stats_kernel(
    const float* __restrict__ a, const float* __restrict__ p,
    const float* __restrict__ n,
    unsigned short* __restrict__ abf, unsigned short* __restrict__ pbf,
    unsigned short* __restrict__ nbf, float* __restrict__ stats)
{
    const int row = blockIdx.x;
    const int t   = threadIdx.x;
    const size_t base = (size_t)row * DIM;

    float4 va = ((const float4*)(a + base))[t];
    float4 vp = ((const float4*)(p + base))[t];
    float4 vn = ((const float4*)(n + base))[t];

    float v[8] = {0,0,0,0,0,0,0,0};   // sa qa sp qp sn qn dap2 dan2
    const float fa[4] = {va.x, va.y, va.z, va.w};
    const float fp[4] = {vp.x, vp.y, vp.z, vp.w};
    const float fn[4] = {vn.x, vn.y, vn.z, vn.w};
#pragma unroll
    for (int e = 0; e < 4; e++) {
        v[0] += fa[e];           v[1] += fa[e] * fa[e];
        v[2] += fp[e];           v[3] += fp[e] * fp[e];
        v[4] += fn[e];           v[5] += fn[e] * fn[e];
        float dp = fa[e] - fp[e] + EPSF;  v[6] += dp * dp;
        float dn = fa[e] - fn[e] + EPSF;  v[7] += dn * dn;
    }

    ushort4 ba, bp, bn;
    ba.x = f2bf(fa[0]); ba.y = f2bf(fa[1]); ba.z = f2bf(fa[2]); ba.w = f2bf(fa[3]);
    bp.x = f2bf(fp[0]); bp.y = f2bf(fp[1]); bp.z = f2bf(fp[2]); bp.w = f2bf(fp[3]);
    bn.x = f2bf(fn[0]); bn.y = f2bf(fn[1]); bn.z = f2bf(fn[2]); bn.w = f2bf(fn[3]);
    ((ushort4*)(abf + base))[t] = ba;
    ((ushort4*)(pbf + base))[t] = bp;
    ((ushort4*)(nbf + base))[t] = bn;

#pragma unroll
    for (int m = 32; m >= 1; m >>= 1)
#pragma unroll
        for (int q = 0; q < 8; q++) v[q] += __shfl_xor(v[q], m);

    __shared__ float part[4][8];
    const int wave = t >> 6, lane = t & 63;
    if (lane == 0)
#pragma unroll
        for (int q = 0; q < 8; q++) part[wave][q] = v[q];
    __syncthreads();
    if (t == 0) {
        float r[8];
#pragma unroll
        for (int q = 0; q < 8; q++)
            r[q] = part[0][q] + part[1][q] + part[2][q] + part[3][q];
        stats[0 * NB + row] = r[1] + 2.0f * EPSF * r[0] + D_EPS2;  // base_a
        stats[1 * NB + row] = r[5] - 2.0f * EPSF * r[4];           // cn
        stats[2 * NB + row] = r[3] - 2.0f * EPSF * r[2];           // cp
        stats[3 * NB + row] = sqrtf(r[6]);                         // d_ap
        stats[4 * NB + row] = sqrtf(r[7]);                         // d_an_row
        ((unsigned*)stats)[5 * NB + row] = 0u;                     // hard_n
        ((unsigned*)stats)[6 * NB + row] = 0x7f800000u;            // hard_p
    }
}

// grid (32, 32): each block computes both A.N^T and A.P^T for its tile.
__global__ __launch_bounds__(256, 2) void gemm_mask_kernel(
    const unsigned short* __restrict__ Abf,
    const unsigned short* __restrict__ Nbf,
    const unsigned short* __restrict__ Pbf,
    float* __restrict__ stats)
{
    const int i0 = blockIdx.x * BM;
    const int j0 = blockIdx.y * BM;

    __shared__ unsigned short sA[BM * BK];   // 8 KB each, unpadded
    __shared__ unsigned short sN[BM * BK];
    __shared__ unsigned short sP[BM * BK];

    const int t    = threadIdx.x;
    const int wave = t >> 6, lane = t & 63;
    const int wm   = wave >> 1, wn = wave & 1;
    const int quad = lane >> 4, lrow = lane & 15;

    // ---- staging pointers: wave stages rows [wave*32, wave*32+32) of each
    // tile; 2 instrs per tile. slot = lane&3, row_local = lane>>2; the chunk
    // loaded into slot s of row r is logical chunk s ^ ((r>>1)&3).
    const int lrow4 = lane >> 2;
    const int kch   = ((lane & 3) ^ ((lane >> 3) & 3)) * 8;
    const size_t grow = (size_t)(wave * 32 + lrow4);
    const unsigned short* ga0 = Abf + (size_t)(i0) * DIM + grow * DIM + kch;
    const unsigned short* gn0 = Nbf + (size_t)(j0) * DIM + grow * DIM + kch;
    const unsigned short* gp0 = Pbf + (size_t)(j0) * DIM + grow * DIM + kch;
    const unsigned short* ga1 = ga0 + 16 * DIM;
    const unsigned short* gn1 = gn0 + 16 * DIM;
    const unsigned short* gp1 = gp0 + 16 * DIM;
    unsigned short* la0 = sA + (wave * 32) * BK;  unsigned short* la1 = la0 + 16 * BK;
    unsigned short* ln0 = sN + (wave * 32) * BK;  unsigned short* ln1 = ln0 + 16 * BK;
    unsigned short* lp0 = sP + (wave * 32) * BK;  unsigned short* lp1 = lp0 + 16 * BK;

    // ---- fragment read pointers (swizzled chunk) ----
    const int rsw = (quad ^ ((lrow >> 1) & 3)) * 8;
    const unsigned short* pa  = sA + (wm * 64 + lrow) * BK + rsw;
    const unsigned short* pbn = sN + (wn * 64 + lrow) * BK + rsw;
    const unsigned short* pbp = sP + (wn * 64 + lrow) * BK + rsw;

    f32x4 accN[4][4], accP[4][4];
#pragma unroll
    for (int im = 0; im < 4; im++)
#pragma unroll
        for (int jn = 0; jn < 4; jn++) {
            accN[im][jn] = (f32x4)(0.0f);
            accP[im][jn] = (f32x4)(0.0f);
        }

    for (int kt = 0; kt < DIM; kt += BK) {
        __syncthreads();   // protect LDS from previous iteration's readers
        g2l16(ga0, la0);  g2l16(ga1, la1);
        g2l16(gn0, ln0);  g2l16(gn1, ln1);
        g2l16(gp0, lp0);  g2l16(gp1, lp1);
        ga0 += BK; ga1 += BK; gn0 += BK; gn1 += BK; gp0 += BK; gp1 += BK;
        __syncthreads();   // drains vmcnt before LDS reads

        bf16x8 afr[4], bn_fr[4], bp_fr[4];
#pragma unroll
        for (int im = 0; im < 4; im++)
            afr[im] = *(const bf16x8*)(pa + im * 16 * BK);
#pragma unroll
        for (int jn = 0; jn < 4; jn++) {
            bn_fr[jn] = *(const bf16x8*)(pbn + jn * 16 * BK);
            bp_fr[jn] = *(const bf16x8*)(pbp + jn * 16 * BK);
        }
#pragma unroll
        for (int im = 0; im < 4; im++)
#pragma unroll
            for (int jn = 0; jn < 4; jn++) {
                accN[im][jn] = __builtin_amdgcn_mfma_f32_16x16x32_bf16(
                    afr[im], bn_fr[jn], accN[im][jn], 0, 0, 0);
                accP[im][jn] = __builtin_amdgcn_mfma_f32_16x16x32_bf16(
                    afr[im], bp_fr[jn], accP[im][jn], 0, 0, 0);
            }
    }

    // epilogue: distances + masks + row reduce + atomics
    const float* __restrict__ base_a = stats + 0 * NB;
    const float* __restrict__ cn_v   = stats + 1 * NB;
    const float* __restrict__ cp_v   = stats + 2 * NB;
    const float* __restrict__ d_ap   = stats + 3 * NB;
    const float* __restrict__ d_an   = stats + 4 * NB;
    unsigned* __restrict__ hard_n = ((unsigned*)stats) + 5 * NB;
    unsigned* __restrict__ hard_p = ((unsigned*)stats) + 6 * NB;

#pragma unroll
    for (int im = 0; im < 4; im++) {
#pragma unroll
        for (int r = 0; r < 4; r++) {
            const int gi = i0 + wm * 64 + im * 16 + quad * 4 + r;
            const float cutN = d_ap[gi];
            const float cutP = d_an[gi];
            const float bi   = base_a[gi];
            float bestN = 0.0f;
            float bestP = __uint_as_float(0x7f800000u);
#pragma unroll
            for (int jn = 0; jn < 4; jn++) {
                const int gj = j0 + wn * 64 + jn * 16 + lrow;
                const float dN = sqrtf(fmaxf(bi + cn_v[gj] - 2.0f * accN[im][jn][r], 0.0f));
                const float dP = sqrtf(fmaxf(bi + cp_v[gj] - 2.0f * accP[im][jn][r], 0.0f));
                if (dN < cutN && dN > bestN) bestN = dN;
                if (dP > cutP && dP < bestP) bestP = dP;
            }
#pragma unroll
            for (int m = 1; m < 16; m <<= 1) {
                bestN = fmaxf(bestN, __shfl_xor(bestN, m));
                bestP = fminf(bestP, __shfl_xor(bestP, m));
            }
            if (lrow == 0) {
                const unsigned bn_ = __float_as_uint(bestN);
                const unsigned bp_ = __float_as_uint(bestP);
                if (bn_ != 0u)          atomicMax(hard_n + gi, bn_);
                if (bp_ != 0x7f800000u) atomicMin(hard_p + gi, bp_);
            }
        }
    }
}

__global__ __launch_bounds__(1024) void finalize_kernel(
    const float* __restrict__ stats, float* __restrict__ out)
{
    const unsigned* hard_n = ((const unsigned*)stats) + 5 * NB;
    const unsigned* hard_p = ((const unsigned*)stats) + 6 * NB;
    const float*    d_ap   = stats + 3 * NB;
    const int t = threadIdx.x;
    const int wave = t >> 6, lane = t & 63;
    __shared__ float pn[16], pp[16];
    __shared__ float s_dan, s_dpp;

    float sn = 0.0f, sp = 0.0f;
    for (int i = t; i < NB; i += 1024) {
        sn += __uint_as_float(hard_n[i]);
        const unsigned hp = hard_p[i];
        if (hp != 0x7f800000u) sp += __uint_as_float(hp);
    }
#pragma unroll
    for (int m = 32; m >= 1; m >>= 1) {
        sn += __shfl_xor(sn, m);
        sp += __shfl_xor(sp, m);
    }
    if (lane == 0) { pn[wave] = sn; pp[wave] = sp; }
    __syncthreads();
    if (t == 0) {
        float an = 0.0f, ap = 0.0f;
#pragma unroll
        for (int w = 0; w < 16; w++) { an += pn[w]; ap += pp[w]; }
        s_dan = an / (float)NB;
        s_dpp = ap / (float)NB;
    }
    __syncthreads();
    const float dan = s_dan, dpp = s_dpp;

    float accv = 0.0f;
    for (int i = t; i < NB; i += 1024)
        accv += fmaxf(d_ap[i] - 0.5f * dpp - 0.5f * dan + 1.0f, 0.0f);
#pragma unroll
    for (int m = 32; m >= 1; m >>= 1) accv += __shfl_xor(accv, m);
    if (lane == 0) pn[wave] = accv;
    __syncthreads();
    if (t == 0) {
        float s = 0.0f;
#pragma unroll
        for (int w = 0; w < 16; w++) s += pn[w];
        out[0] = s / (float)NB;
    }
}

extern "C" void kernel_launch(void* const* d_in, const int* in_sizes, int n_in,
                              void* d_out, int out_size, void* d_ws, size_t ws_size,
                              hipStream_t stream) {
    const float* a = (const float*)d_in[0];
    const float* p = (const float*)d_in[1];
    const float* n = (const float*)d_in[2];
    float* out = (float*)d_out;

    // ws layout: abf | pbf | nbf | stats(7*NB floats)  => ~25.3 MB
    unsigned short* abf = (unsigned short*)d_ws;
    unsigned short* pbf = abf + (size_t)NB * DIM;
    unsigned short* nbf = pbf + (size_t)NB * DIM;
    float* stats = (float*)(nbf + (size_t)NB * DIM);

    row_stats_kernel<<<NB, 256, 0, stream>>>(a, p, n, abf, pbf, nbf, stats);

    dim3 grid(NB / BM, NB / BM);
    gemm_mask_kernel<<<grid, 256, 0, stream>>>(abf, nbf, pbf, stats);

    finalize_kernel<<<1, 1024, 0, stream>>>(stats, out);
}